// Round 7
// baseline (191.152 us; speedup 1.0000x reference)
//
#include <hip/hip_runtime.h>
#include <hip/hip_bf16.h>

// GATConv N=50000, C=64, H=12, E=400000 (+N self loops), x-space aggregation:
//   y[d] = concat_h[ (sum_e w_eh x[s_e]) / (den_h*H) ] @ Wstack,  h never built.
// R9 (176us, k_fused 83.5): readlane/FMA inner loop; VALU-throughput-bound.
// R13 (91us) / R14 (98us): MFMA-aggregation restructures both stall-bound.
// R15 (176.8): split k_main -> k_build + k_ax: NO cost (overlap was worthless,
//   launch ~1us). Aux side = k_pre+k_build+k_ax ~= 92us total, each < 84us
//   (never in top-5). k_fused still VALU-bound: 67% busy, ~5.5K VALU/wave.
// R16 (this round): move broadcast work OFF the VALU pipe, keep structure:
//   (a) w-broadcasts: v_readlane (VALU) -> ds_bpermute uniform-idx
//       (LDS pipe, hardware broadcast, conflict-free; pipe is idle here).
//       [R6's "LDS broadcast" regression was a staged-array round-trip,
//        not bpermute.]
//   (b) readfirstlane on gathered src ids -> saddr-form xb loads (SALU addr).
//   (c) exp->exp2: 1/ln2 folded into Vt in k_pre (commutes with leaky-relu,
//       slope>0); __expf(2 instr) -> v_exp_f32(1).
// No segment_max: exp(s)/sum exp(s) is exact here (logits O(few), fp32 exp).

typedef __bf16 bf16x8 __attribute__((ext_vector_type(8)));
typedef float  f32x4  __attribute__((ext_vector_type(4)));
typedef float  f32x2  __attribute__((ext_vector_type(2)));

#define HEADS 12
#define CH 64
#define HC 768
#define CAP 64
#define ACOLS 24      // a_all[n][0..11]=src logits, [12..23]=dst logits
#define ZSTRIDE 776   // zt row stride (bf16)
#define EPT 4         // edges per thread in k_build
#define RLN2 1.4426950408889634f

__device__ inline float bperm_f(int idx_bytes, float v) {
    return __builtin_bit_cast(float,
        __builtin_amdgcn_ds_bpermute(idx_bytes, __builtin_bit_cast(int, v)));
}

__global__ __launch_bounds__(256) void k_pre(
    const float* __restrict__ W,
    const float* __restrict__ att_src, const float* __restrict__ att_dst,
    int* __restrict__ cnt, __bf16* __restrict__ Wt2, __bf16* __restrict__ Vt,
    int N) {
    const int nb_z = (N + 255) >> 8;
    const int nb_w = (CH * HC) >> 8;           // 192
    int b = blockIdx.x, tid = threadIdx.x;
    if (b < nb_z) {                            // ---- cnt = 0 ----
        int i = b * 256 + tid;
        if (i < N) cnt[i] = 0;
        return;
    }
    b -= nb_z;
    if (b < nb_w) {                            // ---- Wt2 transpose ----
        int t = b * 256 + tid;
        int c = t / HC, kk = t % HC;
        int k = kk & 63;
        Wt2[t] = (__bf16)W[(size_t)k * HC + (kk - k) + c];
        return;
    }
    b -= nb_w;                                 // ---- Vt col b (0..31) ----
    if (b >= 2 * HEADS) {
        if (tid < CH) Vt[b * CH + tid] = (__bf16)0.f;
        return;
    }
    const float* att = (b < HEADS) ? att_src + b * CH
                                   : att_dst + (b - HEADS) * CH;
    int k = tid >> 2, cq = tid & 3;            // 64 k-rows x 4 c-quarters
    const float* wr = W + (size_t)k * HC + (b % HEADS) * CH + cq * 16;
    float s = 0.f;
#pragma unroll
    for (int j = 0; j < 16; ++j) s += wr[j] * att[cq * 16 + j];
    s += __shfl_xor(s, 1, 64);
    s += __shfl_xor(s, 2, 64);
    // R16: logits pre-scaled by 1/ln2 so k_fused uses exp2 directly.
    if (cq == 0) Vt[b * CH + k] = (__bf16)(s * RLN2);
}

// ---- adjacency build, isolated for profiling; 4-deep ILP ----
__global__ __launch_bounds__(256) void k_build(
    const int* __restrict__ ei,
    int* __restrict__ cnt, int* __restrict__ adj, int N, int E) {
    const int EP = E + N;
    int tid0 = blockIdx.x * 256 + threadIdx.x;
    int T = gridDim.x * 256;                   // coalesced grid-stride
    int dv[EPT], sv[EPT];
#pragma unroll
    for (int k = 0; k < EPT; ++k) {            // phase A: all loads in flight
        int e = tid0 + k * T;
        dv[k] = -1; sv[k] = 0;
        if (e < EP) {
            if (e < E) { dv[k] = ei[E + e]; sv[k] = ei[e]; }
            else       { dv[k] = e - E;     sv[k] = dv[k]; }
        }
    }
#pragma unroll
    for (int k = 0; k < EPT; ++k) {            // phase B: atomic+store chains
        if (dv[k] >= 0) {
            int pos = atomicAdd(&cnt[dv[k]], 1);
            if (pos < CAP) adj[dv[k] * CAP + pos] = sv[k];
        }
    }
}

// ---- a_all = x@V + xb, isolated for profiling ----
__global__ __launch_bounds__(256) void k_ax(
    const float* __restrict__ x, const __bf16* __restrict__ Vt,
    __bf16* __restrict__ xb, float* __restrict__ a_all, int N) {
    int tid = threadIdx.x, b = blockIdx.x;
    int wave = tid >> 6, lane = tid & 63;
    int m = lane & 15, quad = lane >> 4;
    int m0 = b * 64 + wave * 16;
    int row = m0 + m;
    int rc = row < N ? row : N - 1;
    const float* xa = x + (size_t)rc * CH + quad * 8;
    f32x4 v0 = *(const f32x4*)xa;
    f32x4 v1 = *(const f32x4*)(xa + 4);
    f32x4 v2 = *(const f32x4*)(xa + 32);
    f32x4 v3 = *(const f32x4*)(xa + 36);
    bf16x8 a0, a1;
#pragma unroll
    for (int j = 0; j < 4; ++j) {
        a0[j] = (__bf16)v0[j]; a0[4 + j] = (__bf16)v1[j];
        a1[j] = (__bf16)v2[j]; a1[4 + j] = (__bf16)v3[j];
    }
    if (row < N) {                             // fused xb = bf16(x)
        *(bf16x8*)(xb + (size_t)row * CH + quad * 8) = a0;
        *(bf16x8*)(xb + (size_t)row * CH + quad * 8 + 32) = a1;
    }
#pragma unroll
    for (int t = 0; t < 2; ++t) {              // two 16-col tiles -> 24 cols
        const __bf16* bp = Vt + (size_t)(t * 16 + m) * CH + quad * 8;
        bf16x8 b0 = *(const bf16x8*)bp;
        bf16x8 b1 = *(const bf16x8*)(bp + 32);
        f32x4 acc = {0.f, 0.f, 0.f, 0.f};
        acc = __builtin_amdgcn_mfma_f32_16x16x32_bf16(a0, b0, acc, 0, 0, 0);
        acc = __builtin_amdgcn_mfma_f32_16x16x32_bf16(a1, b1, acc, 0, 0, 0);
        int col = t * 16 + m;
        if (col < ACOLS) {
#pragma unroll
            for (int r = 0; r < 4; ++r) {
                int rr = m0 + quad * 4 + r;
                if (rr < N) a_all[(size_t)rr * ACOLS + col] = acc[r];
            }
        }
    }
}

__global__ __launch_bounds__(256) void k_fused(
    const int* __restrict__ cnt, const int* __restrict__ adj,
    const float* __restrict__ a_all,
    const __bf16* __restrict__ xb, const __bf16* __restrict__ Wt2,
    const float* __restrict__ x, const float* __restrict__ bias,
    float* __restrict__ out, int N) {
    __shared__ __bf16 zt[16 * ZSTRIDE];
    int lane = threadIdx.x & 63;
    int wave = __builtin_amdgcn_readfirstlane(threadIdx.x >> 6);
    int base = blockIdx.x * 16;

    // ---- prologue: 4 nodes' cnt + adj[0..31] in parallel ----
    int degj[4], slj[4];
#pragma unroll
    for (int j = 0; j < 4; ++j) {
        int d = base + wave * 4 + j;
        int dg = __builtin_amdgcn_readfirstlane(cnt[d]);
        degj[j] = dg < CAP ? dg : CAP;
        int sraw = 0;
        if (lane < 32) sraw = adj[d * CAP + lane];   // half row; poison past deg
        slj[j] = sraw;
    }

#pragma unroll
    for (int j = 0; j < 4; ++j) {
        int row = wave * 4 + j;
        int d = base + row;
        int deg = degj[j];
        int s_l = slj[j];
        if (deg > 32 && lane >= 32)              // ~never (Poisson(9))
            s_l = adj[d * CAP + lane];
        s_l = s_l < 0 ? 0 : (s_l >= N ? N - 1 : s_l);  // clamp poison

        // ---- phase 1: lane = edge slot; 12 weights in VGPRs ----
        float adf[HEADS];
        {
            const f32x4* p = (const f32x4*)(a_all + (size_t)d * ACOLS + HEADS);
            f32x4 t0 = p[0], t1 = p[1], t2 = p[2];
#pragma unroll
            for (int u = 0; u < 4; ++u) { adf[u] = t0[u]; adf[4 + u] = t1[u]; adf[8 + u] = t2[u]; }
        }
        float w[HEADS];
        {
            const f32x4* p = (const f32x4*)(a_all + (size_t)s_l * ACOLS);
            f32x4 t0 = p[0], t1 = p[1], t2 = p[2];
            float asf[HEADS];
#pragma unroll
            for (int u = 0; u < 4; ++u) { asf[u] = t0[u]; asf[4 + u] = t1[u]; asf[8 + u] = t2[u]; }
#pragma unroll
            for (int hh = 0; hh < HEADS; ++hh) {
                float sc = asf[hh] + adf[hh];
                sc = sc > 0.f ? sc : 0.2f * sc;     // logits pre-scaled by 1/ln2
                w[hh] = __builtin_amdgcn_exp2f(sc); // lanes >= deg never read
            }
        }

        // ---- phase 2: bpermute broadcast (LDS pipe), {acc,den} f32x2 ----
        f32x2 acc2[HEADS];
#pragma unroll
        for (int hh = 0; hh < HEADS; ++hh) acc2[hh] = (f32x2){0.f, 0.f};
        int i = 0;
        for (; i + 3 < deg; i += 4) {
            int s0 = __builtin_amdgcn_readfirstlane(__builtin_amdgcn_readlane(s_l, i));
            int s1 = __builtin_amdgcn_readfirstlane(__builtin_amdgcn_readlane(s_l, i + 1));
            int s2 = __builtin_amdgcn_readfirstlane(__builtin_amdgcn_readlane(s_l, i + 2));
            int s3 = __builtin_amdgcn_readfirstlane(__builtin_amdgcn_readlane(s_l, i + 3));
            f32x2 xv0 = {(float)xb[(size_t)s0 * CH + lane], 1.f};
            f32x2 xv1 = {(float)xb[(size_t)s1 * CH + lane], 1.f};
            f32x2 xv2 = {(float)xb[(size_t)s2 * CH + lane], 1.f};
            f32x2 xv3 = {(float)xb[(size_t)s3 * CH + lane], 1.f};
            int b0 = i << 2, b1 = (i + 1) << 2, b2 = (i + 2) << 2, b3 = (i + 3) << 2;
#pragma unroll
            for (int hh = 0; hh < HEADS; ++hh) {
                float w0 = bperm_f(b0, w[hh]);
                float w1 = bperm_f(b1, w[hh]);
                float w2 = bperm_f(b2, w[hh]);
                float w3 = bperm_f(b3, w[hh]);
                acc2[hh] += (f32x2){w0, w0} * xv0;
                acc2[hh] += (f32x2){w1, w1} * xv1;
                acc2[hh] += (f32x2){w2, w2} * xv2;
                acc2[hh] += (f32x2){w3, w3} * xv3;
            }
        }
        for (; i < deg; ++i) {
            int s = __builtin_amdgcn_readfirstlane(__builtin_amdgcn_readlane(s_l, i));
            f32x2 xv = {(float)xb[(size_t)s * CH + lane], 1.f};
            int bi = i << 2;
#pragma unroll
            for (int hh = 0; hh < HEADS; ++hh) {
                float wv = bperm_f(bi, w[hh]);
                acc2[hh] += (f32x2){wv, wv} * xv;
            }
        }
        __bf16* zr = zt + row * ZSTRIDE + lane;
#pragma unroll
        for (int hh = 0; hh < HEADS; ++hh)
            zr[hh * CH] = (__bf16)(acc2[hh].x * (1.0f / ((acc2[hh].y + 1e-16f) * HEADS)));
    }

    __syncthreads();

    // ---- phase 3: 16x64x768 GEMM; wave = one 16-col tile ----
    {
        int m = lane & 15, quad = lane >> 4;
        int n0 = wave * 16;
        const __bf16* za = zt + m * ZSTRIDE + quad * 8;
        const __bf16* wb = Wt2 + (size_t)(n0 + m) * HC + quad * 8;
        f32x4 acc = {0.f, 0.f, 0.f, 0.f};
#pragma unroll
        for (int kc = 0; kc < HC; kc += 32) {
            bf16x8 a  = *(const bf16x8*)(za + kc);
            bf16x8 bf = *(const bf16x8*)(wb + kc);
            acc = __builtin_amdgcn_mfma_f32_16x16x32_bf16(a, bf, acc, 0, 0, 0);
        }
        int col = n0 + m;
        float bv = bias[col];
#pragma unroll
        for (int r = 0; r < 4; ++r) {
            int dd = base + quad * 4 + r;
            if (dd < N) {
                float o = x[(size_t)dd * CH + col] + acc[r] + bv;
                out[(size_t)dd * CH + col] = fmaxf(o, 0.f);
            }
        }
    }
}

extern "C" void kernel_launch(void* const* d_in, const int* in_sizes, int n_in,
                              void* d_out, int out_size, void* d_ws, size_t ws_size,
                              hipStream_t stream) {
    const float* x       = (const float*)d_in[0];
    const int*   ei      = (const int*)d_in[1];
    const float* W       = (const float*)d_in[2];
    const float* att_src = (const float*)d_in[3];
    const float* att_dst = (const float*)d_in[4];
    const float* bias    = (const float*)d_in[5];
    float* out = (float*)d_out;

    int N = in_sizes[0] / CH;   // 50000
    int E = in_sizes[1] / 2;    // 400000
    int EP = E + N;

    char* ws = (char*)d_ws;
    size_t off = 0;
    auto take = [&](size_t bytes) -> void* {
        void* p = ws + off;
        off = (off + bytes + 255) & ~(size_t)255;
        return p;
    };
    __bf16* xb    = (__bf16*)take((size_t)N * CH * sizeof(__bf16));
    __bf16* Wt2   = (__bf16*)take((size_t)CH * HC * sizeof(__bf16));
    __bf16* Vt    = (__bf16*)take((size_t)32 * CH * sizeof(__bf16));
    float*  a_all = (float*)take((size_t)N * ACOLS * sizeof(float));
    int*    adj   = (int*)take((size_t)N * CAP * sizeof(int));
    int*    cnt   = (int*)take((size_t)N * sizeof(int));

    const int nb_z     = (N + 255) / 256;
    const int nb_w     = (CH * HC) / 256;
    const int nb_build = (EP + EPT * 256 - 1) / (EPT * 256);   // 440
    const int nb_ax    = (N + 63) / 64;

    k_pre<<<nb_z + nb_w + 32, 256, 0, stream>>>(W, att_src, att_dst, cnt, Wt2, Vt, N);
    k_build<<<nb_build, 256, 0, stream>>>(ei, cnt, adj, N, E);
    k_ax<<<nb_ax, 256, 0, stream>>>(x, Vt, xb, a_all, N);
    k_fused<<<(N + 15) / 16, 256, 0, stream>>>(cnt, adj, a_all, xb, Wt2, x, bias, out, N);
}

// Round 8
// 185.361 us; speedup vs baseline: 1.0312x; 1.0312x over previous
//
#include <hip/hip_runtime.h>
#include <hip/hip_bf16.h>

// GATConv N=50000, C=64, H=12, E=400000 (+N self loops), x-space aggregation:
//   y[d] = concat_h[ (sum_e w_eh x[s_e]) / (den_h*H) ] @ Wstack,  h never built.
// R9 (176us, k_fused 83.5) / R15 (176.8, k_fused 83.7-86.6): best verified.
// R13 (VALU 22%, 91us) R14 (31%, 98us) R16 (41%, 94.5us): three independent
//   falsifications -- cutting VALU issue NEVER helps. k_fused is NOT
//   VALU-throughput-bound; VALUBusy ~70% is concurrent, not critical-path.
// R17 (this round): the counters' surviving story: FETCH_SIZE 56MB == xb
//   edge-gather traffic (450K edges x 128B random rows) at 820 GB/s
//   effective == ~68us ~= k_fused duration. 820 GB/s is a CONCURRENCY limit
//   (Little's law): phase 2 keeps only 4 gathers (512B) in flight per wave.
//   Change (single variable vs R15): leading 8-edge batch in phase 2 ->
//   1KB in flight during load windows. No launch_bounds / masking / ushort
//   staging (the R10 confounders). All R16 edits reverted.
// No segment_max: exp(s)/sum exp(s) is exact here (logits O(few), fp32 exp).

typedef __bf16 bf16x8 __attribute__((ext_vector_type(8)));
typedef float  f32x4  __attribute__((ext_vector_type(4)));
typedef float  f32x2  __attribute__((ext_vector_type(2)));

#define HEADS 12
#define CH 64
#define HC 768
#define CAP 64
#define ACOLS 24      // a_all[n][0..11]=src logits, [12..23]=dst logits
#define ZSTRIDE 776   // zt row stride (bf16)
#define EPT 4         // edges per thread in k_build

__device__ inline float readlane_f(float v, int lane) {
    return __builtin_bit_cast(float,
        __builtin_amdgcn_readlane(__builtin_bit_cast(int, v), lane));
}

__global__ __launch_bounds__(256) void k_pre(
    const float* __restrict__ W,
    const float* __restrict__ att_src, const float* __restrict__ att_dst,
    int* __restrict__ cnt, __bf16* __restrict__ Wt2, __bf16* __restrict__ Vt,
    int N) {
    const int nb_z = (N + 255) >> 8;
    const int nb_w = (CH * HC) >> 8;           // 192
    int b = blockIdx.x, tid = threadIdx.x;
    if (b < nb_z) {                            // ---- cnt = 0 ----
        int i = b * 256 + tid;
        if (i < N) cnt[i] = 0;
        return;
    }
    b -= nb_z;
    if (b < nb_w) {                            // ---- Wt2 transpose ----
        int t = b * 256 + tid;
        int c = t / HC, kk = t % HC;
        int k = kk & 63;
        Wt2[t] = (__bf16)W[(size_t)k * HC + (kk - k) + c];
        return;
    }
    b -= nb_w;                                 // ---- Vt col b (0..31) ----
    if (b >= 2 * HEADS) {
        if (tid < CH) Vt[b * CH + tid] = (__bf16)0.f;
        return;
    }
    const float* att = (b < HEADS) ? att_src + b * CH
                                   : att_dst + (b - HEADS) * CH;
    int k = tid >> 2, cq = tid & 3;            // 64 k-rows x 4 c-quarters
    const float* wr = W + (size_t)k * HC + (b % HEADS) * CH + cq * 16;
    float s = 0.f;
#pragma unroll
    for (int j = 0; j < 16; ++j) s += wr[j] * att[cq * 16 + j];
    s += __shfl_xor(s, 1, 64);
    s += __shfl_xor(s, 2, 64);
    if (cq == 0) Vt[b * CH + k] = (__bf16)s;
}

// ---- adjacency build, isolated for profiling; 4-deep ILP ----
__global__ __launch_bounds__(256) void k_build(
    const int* __restrict__ ei,
    int* __restrict__ cnt, int* __restrict__ adj, int N, int E) {
    const int EP = E + N;
    int tid0 = blockIdx.x * 256 + threadIdx.x;
    int T = gridDim.x * 256;                   // coalesced grid-stride
    int dv[EPT], sv[EPT];
#pragma unroll
    for (int k = 0; k < EPT; ++k) {            // phase A: all loads in flight
        int e = tid0 + k * T;
        dv[k] = -1; sv[k] = 0;
        if (e < EP) {
            if (e < E) { dv[k] = ei[E + e]; sv[k] = ei[e]; }
            else       { dv[k] = e - E;     sv[k] = dv[k]; }
        }
    }
#pragma unroll
    for (int k = 0; k < EPT; ++k) {            // phase B: atomic+store chains
        if (dv[k] >= 0) {
            int pos = atomicAdd(&cnt[dv[k]], 1);
            if (pos < CAP) adj[dv[k] * CAP + pos] = sv[k];
        }
    }
}

// ---- a_all = x@V + xb, isolated for profiling ----
__global__ __launch_bounds__(256) void k_ax(
    const float* __restrict__ x, const __bf16* __restrict__ Vt,
    __bf16* __restrict__ xb, float* __restrict__ a_all, int N) {
    int tid = threadIdx.x, b = blockIdx.x;
    int wave = tid >> 6, lane = tid & 63;
    int m = lane & 15, quad = lane >> 4;
    int m0 = b * 64 + wave * 16;
    int row = m0 + m;
    int rc = row < N ? row : N - 1;
    const float* xa = x + (size_t)rc * CH + quad * 8;
    f32x4 v0 = *(const f32x4*)xa;
    f32x4 v1 = *(const f32x4*)(xa + 4);
    f32x4 v2 = *(const f32x4*)(xa + 32);
    f32x4 v3 = *(const f32x4*)(xa + 36);
    bf16x8 a0, a1;
#pragma unroll
    for (int j = 0; j < 4; ++j) {
        a0[j] = (__bf16)v0[j]; a0[4 + j] = (__bf16)v1[j];
        a1[j] = (__bf16)v2[j]; a1[4 + j] = (__bf16)v3[j];
    }
    if (row < N) {                             // fused xb = bf16(x)
        *(bf16x8*)(xb + (size_t)row * CH + quad * 8) = a0;
        *(bf16x8*)(xb + (size_t)row * CH + quad * 8 + 32) = a1;
    }
#pragma unroll
    for (int t = 0; t < 2; ++t) {              // two 16-col tiles -> 24 cols
        const __bf16* bp = Vt + (size_t)(t * 16 + m) * CH + quad * 8;
        bf16x8 b0 = *(const bf16x8*)bp;
        bf16x8 b1 = *(const bf16x8*)(bp + 32);
        f32x4 acc = {0.f, 0.f, 0.f, 0.f};
        acc = __builtin_amdgcn_mfma_f32_16x16x32_bf16(a0, b0, acc, 0, 0, 0);
        acc = __builtin_amdgcn_mfma_f32_16x16x32_bf16(a1, b1, acc, 0, 0, 0);
        int col = t * 16 + m;
        if (col < ACOLS) {
#pragma unroll
            for (int r = 0; r < 4; ++r) {
                int rr = m0 + quad * 4 + r;
                if (rr < N) a_all[(size_t)rr * ACOLS + col] = acc[r];
            }
        }
    }
}

__global__ __launch_bounds__(256) void k_fused(
    const int* __restrict__ cnt, const int* __restrict__ adj,
    const float* __restrict__ a_all,
    const __bf16* __restrict__ xb, const __bf16* __restrict__ Wt2,
    const float* __restrict__ x, const float* __restrict__ bias,
    float* __restrict__ out, int N) {
    __shared__ __bf16 zt[16 * ZSTRIDE];
    int lane = threadIdx.x & 63;
    int wave = __builtin_amdgcn_readfirstlane(threadIdx.x >> 6);
    int base = blockIdx.x * 16;

    // ---- prologue: 4 nodes' cnt + adj[0..31] in parallel ----
    int degj[4], slj[4];
#pragma unroll
    for (int j = 0; j < 4; ++j) {
        int d = base + wave * 4 + j;
        int dg = __builtin_amdgcn_readfirstlane(cnt[d]);
        degj[j] = dg < CAP ? dg : CAP;
        int sraw = 0;
        if (lane < 32) sraw = adj[d * CAP + lane];   // half row; poison past deg
        slj[j] = sraw;
    }

#pragma unroll
    for (int j = 0; j < 4; ++j) {
        int row = wave * 4 + j;
        int d = base + row;
        int deg = degj[j];
        int s_l = slj[j];
        if (deg > 32 && lane >= 32)              // ~never (Poisson(9))
            s_l = adj[d * CAP + lane];
        s_l = s_l < 0 ? 0 : (s_l >= N ? N - 1 : s_l);  // clamp poison

        // ---- phase 1: lane = edge slot; 12 weights in VGPRs ----
        float adf[HEADS];
        {
            const f32x4* p = (const f32x4*)(a_all + (size_t)d * ACOLS + HEADS);
            f32x4 t0 = p[0], t1 = p[1], t2 = p[2];
#pragma unroll
            for (int u = 0; u < 4; ++u) { adf[u] = t0[u]; adf[4 + u] = t1[u]; adf[8 + u] = t2[u]; }
        }
        float w[HEADS];
        {
            const f32x4* p = (const f32x4*)(a_all + (size_t)s_l * ACOLS);
            f32x4 t0 = p[0], t1 = p[1], t2 = p[2];
            float asf[HEADS];
#pragma unroll
            for (int u = 0; u < 4; ++u) { asf[u] = t0[u]; asf[4 + u] = t1[u]; asf[8 + u] = t2[u]; }
#pragma unroll
            for (int hh = 0; hh < HEADS; ++hh) {
                float sc = asf[hh] + adf[hh];
                sc = sc > 0.f ? sc : 0.2f * sc;
                w[hh] = __expf(sc);              // lanes >= deg never read
            }
        }

        // ---- phase 2: readlane broadcast, {acc,den} f32x2 packed ----
        // R17: leading 8-edge batch -> 8 gathers (1KB) in flight per wave
        // during the load window (was 4/512B; Little's law on random xb
        // rows at ~600ns latency was capping effective BW at ~820GB/s).
        f32x2 acc2[HEADS];
#pragma unroll
        for (int hh = 0; hh < HEADS; ++hh) acc2[hh] = (f32x2){0.f, 0.f};
        int i = 0;
        for (; i + 7 < deg; i += 8) {
            int s8[8];
#pragma unroll
            for (int q = 0; q < 8; ++q)
                s8[q] = __builtin_amdgcn_readlane(s_l, i + q);
            f32x2 xv[8];
#pragma unroll
            for (int q = 0; q < 8; ++q)
                xv[q] = (f32x2){(float)xb[(size_t)s8[q] * CH + lane], 1.f};
#pragma unroll
            for (int hh = 0; hh < HEADS; ++hh) {
#pragma unroll
                for (int q = 0; q < 8; ++q) {
                    float wq = readlane_f(w[hh], i + q);
                    acc2[hh] += (f32x2){wq, wq} * xv[q];
                }
            }
        }
        for (; i + 3 < deg; i += 4) {
            int s0 = __builtin_amdgcn_readlane(s_l, i);
            int s1 = __builtin_amdgcn_readlane(s_l, i + 1);
            int s2 = __builtin_amdgcn_readlane(s_l, i + 2);
            int s3 = __builtin_amdgcn_readlane(s_l, i + 3);
            f32x2 xv0 = {(float)xb[(size_t)s0 * CH + lane], 1.f};
            f32x2 xv1 = {(float)xb[(size_t)s1 * CH + lane], 1.f};
            f32x2 xv2 = {(float)xb[(size_t)s2 * CH + lane], 1.f};
            f32x2 xv3 = {(float)xb[(size_t)s3 * CH + lane], 1.f};
#pragma unroll
            for (int hh = 0; hh < HEADS; ++hh) {
                float w0 = readlane_f(w[hh], i);
                float w1 = readlane_f(w[hh], i + 1);
                float w2 = readlane_f(w[hh], i + 2);
                float w3 = readlane_f(w[hh], i + 3);
                acc2[hh] += (f32x2){w0, w0} * xv0;
                acc2[hh] += (f32x2){w1, w1} * xv1;
                acc2[hh] += (f32x2){w2, w2} * xv2;
                acc2[hh] += (f32x2){w3, w3} * xv3;
            }
        }
        for (; i < deg; ++i) {
            int s = __builtin_amdgcn_readlane(s_l, i);
            f32x2 xv = {(float)xb[(size_t)s * CH + lane], 1.f};
#pragma unroll
            for (int hh = 0; hh < HEADS; ++hh) {
                float wv = readlane_f(w[hh], i);
                acc2[hh] += (f32x2){wv, wv} * xv;
            }
        }
        __bf16* zr = zt + row * ZSTRIDE + lane;
#pragma unroll
        for (int hh = 0; hh < HEADS; ++hh)
            zr[hh * CH] = (__bf16)(acc2[hh].x * (1.0f / ((acc2[hh].y + 1e-16f) * HEADS)));
    }

    __syncthreads();

    // ---- phase 3: 16x64x768 GEMM; wave = one 16-col tile ----
    {
        int m = lane & 15, quad = lane >> 4;
        int n0 = wave * 16;
        const __bf16* za = zt + m * ZSTRIDE + quad * 8;
        const __bf16* wb = Wt2 + (size_t)(n0 + m) * HC + quad * 8;
        f32x4 acc = {0.f, 0.f, 0.f, 0.f};
#pragma unroll
        for (int kc = 0; kc < HC; kc += 32) {
            bf16x8 a  = *(const bf16x8*)(za + kc);
            bf16x8 bf = *(const bf16x8*)(wb + kc);
            acc = __builtin_amdgcn_mfma_f32_16x16x32_bf16(a, bf, acc, 0, 0, 0);
        }
        int col = n0 + m;
        float bv = bias[col];
#pragma unroll
        for (int r = 0; r < 4; ++r) {
            int dd = base + quad * 4 + r;
            if (dd < N) {
                float o = x[(size_t)dd * CH + col] + acc[r] + bv;
                out[(size_t)dd * CH + col] = fmaxf(o, 0.f);
            }
        }
    }
}

extern "C" void kernel_launch(void* const* d_in, const int* in_sizes, int n_in,
                              void* d_out, int out_size, void* d_ws, size_t ws_size,
                              hipStream_t stream) {
    const float* x       = (const float*)d_in[0];
    const int*   ei      = (const int*)d_in[1];
    const float* W       = (const float*)d_in[2];
    const float* att_src = (const float*)d_in[3];
    const float* att_dst = (const float*)d_in[4];
    const float* bias    = (const float*)d_in[5];
    float* out = (float*)d_out;

    int N = in_sizes[0] / CH;   // 50000
    int E = in_sizes[1] / 2;    // 400000
    int EP = E + N;

    char* ws = (char*)d_ws;
    size_t off = 0;
    auto take = [&](size_t bytes) -> void* {
        void* p = ws + off;
        off = (off + bytes + 255) & ~(size_t)255;
        return p;
    };
    __bf16* xb    = (__bf16*)take((size_t)N * CH * sizeof(__bf16));
    __bf16* Wt2   = (__bf16*)take((size_t)CH * HC * sizeof(__bf16));
    __bf16* Vt    = (__bf16*)take((size_t)32 * CH * sizeof(__bf16));
    float*  a_all = (float*)take((size_t)N * ACOLS * sizeof(float));
    int*    adj   = (int*)take((size_t)N * CAP * sizeof(int));
    int*    cnt   = (int*)take((size_t)N * sizeof(int));

    const int nb_z     = (N + 255) / 256;
    const int nb_w     = (CH * HC) / 256;
    const int nb_build = (EP + EPT * 256 - 1) / (EPT * 256);   // 440
    const int nb_ax    = (N + 63) / 64;

    k_pre<<<nb_z + nb_w + 32, 256, 0, stream>>>(W, att_src, att_dst, cnt, Wt2, Vt, N);
    k_build<<<nb_build, 256, 0, stream>>>(ei, cnt, adj, N, E);
    k_ax<<<nb_ax, 256, 0, stream>>>(x, Vt, xb, a_all, N);
    k_fused<<<(N + 15) / 16, 256, 0, stream>>>(cnt, adj, a_all, xb, Wt2, x, bias, out, N);
}

// Round 9
// 185.271 us; speedup vs baseline: 1.0317x; 1.0005x over previous
//
#include <hip/hip_runtime.h>
#include <hip/hip_bf16.h>

// GATConv N=50000, C=64, H=12, E=400000 (+N self loops), x-space aggregation:
//   y[d] = concat_h[ (sum_e w_eh x[s_e]) / (den_h*H) ] @ Wstack,  h never built.
// R9/R15/R17 (~176-185us, k_fused 81-84): best verified structure.
// Falsified: VALU-throughput (R13/14/16: cutting VALU never helps),
//   gather depth (R17: 8-deep neutral), occupancy (42-50% no effect).
// R18 (this round): TA-serialization theory. Phase-1 src a_all gather runs
//   on ALL 64 lanes; lanes >= deg use clamped POISON addresses -> 3 x f32x4
//   instrs each touching ~64 distinct random rows -> ~60 TA address probes
//   per instr serialized at the per-CU TA. ~15us/CU of TA occupancy, shared
//   by all waves; invisible in VALUBusy AND in FETCH (a_all is L2/L3-
//   resident). Fix: exec-mask the gather to lane<deg (zero-init frags; dead
//   lanes' w finite, never broadcast). R10 bundled this mask with the
//   launch_bounds spill-storm -- never cleanly tested until now.
//   Aux (independent kernels): cnt=0 via hipMemsetAsync (capture-safe),
//   k_pre loses its 196 zeroing blocks.
// No segment_max: exp(s)/sum exp(s) is exact here (logits O(few), fp32 exp).

typedef __bf16 bf16x8 __attribute__((ext_vector_type(8)));
typedef float  f32x4  __attribute__((ext_vector_type(4)));
typedef float  f32x2  __attribute__((ext_vector_type(2)));

#define HEADS 12
#define CH 64
#define HC 768
#define CAP 64
#define ACOLS 24      // a_all[n][0..11]=src logits, [12..23]=dst logits
#define ZSTRIDE 776   // zt row stride (bf16)
#define EPT 4         // edges per thread in k_build

__device__ inline float readlane_f(float v, int lane) {
    return __builtin_bit_cast(float,
        __builtin_amdgcn_readlane(__builtin_bit_cast(int, v), lane));
}

__global__ __launch_bounds__(256) void k_pre(
    const float* __restrict__ W,
    const float* __restrict__ att_src, const float* __restrict__ att_dst,
    __bf16* __restrict__ Wt2, __bf16* __restrict__ Vt) {
    const int nb_w = (CH * HC) >> 8;           // 192
    int b = blockIdx.x, tid = threadIdx.x;
    if (b < nb_w) {                            // ---- Wt2 transpose ----
        int t = b * 256 + tid;
        int c = t / HC, kk = t % HC;
        int k = kk & 63;
        Wt2[t] = (__bf16)W[(size_t)k * HC + (kk - k) + c];
        return;
    }
    b -= nb_w;                                 // ---- Vt col b (0..31) ----
    if (b >= 2 * HEADS) {
        if (tid < CH) Vt[b * CH + tid] = (__bf16)0.f;
        return;
    }
    const float* att = (b < HEADS) ? att_src + b * CH
                                   : att_dst + (b - HEADS) * CH;
    int k = tid >> 2, cq = tid & 3;            // 64 k-rows x 4 c-quarters
    const float* wr = W + (size_t)k * HC + (b % HEADS) * CH + cq * 16;
    float s = 0.f;
#pragma unroll
    for (int j = 0; j < 16; ++j) s += wr[j] * att[cq * 16 + j];
    s += __shfl_xor(s, 1, 64);
    s += __shfl_xor(s, 2, 64);
    if (cq == 0) Vt[b * CH + k] = (__bf16)s;
}

// ---- adjacency build, isolated for profiling; 4-deep ILP ----
__global__ __launch_bounds__(256) void k_build(
    const int* __restrict__ ei,
    int* __restrict__ cnt, int* __restrict__ adj, int N, int E) {
    const int EP = E + N;
    int tid0 = blockIdx.x * 256 + threadIdx.x;
    int T = gridDim.x * 256;                   // coalesced grid-stride
    int dv[EPT], sv[EPT];
#pragma unroll
    for (int k = 0; k < EPT; ++k) {            // phase A: all loads in flight
        int e = tid0 + k * T;
        dv[k] = -1; sv[k] = 0;
        if (e < EP) {
            if (e < E) { dv[k] = ei[E + e]; sv[k] = ei[e]; }
            else       { dv[k] = e - E;     sv[k] = dv[k]; }
        }
    }
#pragma unroll
    for (int k = 0; k < EPT; ++k) {            // phase B: atomic+store chains
        if (dv[k] >= 0) {
            int pos = atomicAdd(&cnt[dv[k]], 1);
            if (pos < CAP) adj[dv[k] * CAP + pos] = sv[k];
        }
    }
}

// ---- a_all = x@V + xb, isolated for profiling ----
__global__ __launch_bounds__(256) void k_ax(
    const float* __restrict__ x, const __bf16* __restrict__ Vt,
    __bf16* __restrict__ xb, float* __restrict__ a_all, int N) {
    int tid = threadIdx.x, b = blockIdx.x;
    int wave = tid >> 6, lane = tid & 63;
    int m = lane & 15, quad = lane >> 4;
    int m0 = b * 64 + wave * 16;
    int row = m0 + m;
    int rc = row < N ? row : N - 1;
    const float* xa = x + (size_t)rc * CH + quad * 8;
    f32x4 v0 = *(const f32x4*)xa;
    f32x4 v1 = *(const f32x4*)(xa + 4);
    f32x4 v2 = *(const f32x4*)(xa + 32);
    f32x4 v3 = *(const f32x4*)(xa + 36);
    bf16x8 a0, a1;
#pragma unroll
    for (int j = 0; j < 4; ++j) {
        a0[j] = (__bf16)v0[j]; a0[4 + j] = (__bf16)v1[j];
        a1[j] = (__bf16)v2[j]; a1[4 + j] = (__bf16)v3[j];
    }
    if (row < N) {                             // fused xb = bf16(x)
        *(bf16x8*)(xb + (size_t)row * CH + quad * 8) = a0;
        *(bf16x8*)(xb + (size_t)row * CH + quad * 8 + 32) = a1;
    }
#pragma unroll
    for (int t = 0; t < 2; ++t) {              // two 16-col tiles -> 24 cols
        const __bf16* bp = Vt + (size_t)(t * 16 + m) * CH + quad * 8;
        bf16x8 b0 = *(const bf16x8*)bp;
        bf16x8 b1 = *(const bf16x8*)(bp + 32);
        f32x4 acc = {0.f, 0.f, 0.f, 0.f};
        acc = __builtin_amdgcn_mfma_f32_16x16x32_bf16(a0, b0, acc, 0, 0, 0);
        acc = __builtin_amdgcn_mfma_f32_16x16x32_bf16(a1, b1, acc, 0, 0, 0);
        int col = t * 16 + m;
        if (col < ACOLS) {
#pragma unroll
            for (int r = 0; r < 4; ++r) {
                int rr = m0 + quad * 4 + r;
                if (rr < N) a_all[(size_t)rr * ACOLS + col] = acc[r];
            }
        }
    }
}

__global__ __launch_bounds__(256) void k_fused(
    const int* __restrict__ cnt, const int* __restrict__ adj,
    const float* __restrict__ a_all,
    const __bf16* __restrict__ xb, const __bf16* __restrict__ Wt2,
    const float* __restrict__ x, const float* __restrict__ bias,
    float* __restrict__ out, int N) {
    __shared__ __bf16 zt[16 * ZSTRIDE];
    int lane = threadIdx.x & 63;
    int wave = __builtin_amdgcn_readfirstlane(threadIdx.x >> 6);
    int base = blockIdx.x * 16;

    // ---- prologue: 4 nodes' cnt + adj[0..31] in parallel ----
    int degj[4], slj[4];
#pragma unroll
    for (int j = 0; j < 4; ++j) {
        int d = base + wave * 4 + j;
        int dg = __builtin_amdgcn_readfirstlane(cnt[d]);
        degj[j] = dg < CAP ? dg : CAP;
        int sraw = 0;
        if (lane < 32) sraw = adj[d * CAP + lane];   // half row; garbage past deg
        slj[j] = sraw;
    }

#pragma unroll
    for (int j = 0; j < 4; ++j) {
        int row = wave * 4 + j;
        int d = base + row;
        int deg = degj[j];
        int s_l = slj[j];
        if (deg > 32 && lane >= 32)              // ~never (Poisson(9))
            s_l = adj[d * CAP + lane];
        s_l = s_l < 0 ? 0 : (s_l >= N ? N - 1 : s_l);  // clamp (cheap safety)

        // ---- phase 1: lane = edge slot; 12 weights in VGPRs ----
        float adf[HEADS];
        {
            const f32x4* p = (const f32x4*)(a_all + (size_t)d * ACOLS + HEADS);
            f32x4 t0 = p[0], t1 = p[1], t2 = p[2];
#pragma unroll
            for (int u = 0; u < 4; ++u) { adf[u] = t0[u]; adf[4 + u] = t1[u]; adf[8 + u] = t2[u]; }
        }
        float w[HEADS];
        {
            // R18: exec-masked src gather. Unmasked, lanes >= deg probed ~55
            // random poison rows -> ~60 serialized TA address probes per
            // f32x4 instr, ~15us/CU of TA occupancy (L2/L3-resident, so no
            // FETCH signal). Masked: ~deg probes. Single variable vs R17.
            f32x4 t0 = {0.f, 0.f, 0.f, 0.f};
            f32x4 t1 = {0.f, 0.f, 0.f, 0.f};
            f32x4 t2 = {0.f, 0.f, 0.f, 0.f};
            if (lane < deg) {
                const f32x4* p = (const f32x4*)(a_all + (size_t)s_l * ACOLS);
                t0 = p[0]; t1 = p[1]; t2 = p[2];
            }
            float asf[HEADS];
#pragma unroll
            for (int u = 0; u < 4; ++u) { asf[u] = t0[u]; asf[4 + u] = t1[u]; asf[8 + u] = t2[u]; }
#pragma unroll
            for (int hh = 0; hh < HEADS; ++hh) {
                float sc = asf[hh] + adf[hh];
                sc = sc > 0.f ? sc : 0.2f * sc;
                w[hh] = __expf(sc);              // lanes >= deg: finite, never read
            }
        }

        // ---- phase 2: readlane broadcast, {acc,den} f32x2 packed ----
        f32x2 acc2[HEADS];
#pragma unroll
        for (int hh = 0; hh < HEADS; ++hh) acc2[hh] = (f32x2){0.f, 0.f};
        int i = 0;
        for (; i + 7 < deg; i += 8) {
            int s8[8];
#pragma unroll
            for (int q = 0; q < 8; ++q)
                s8[q] = __builtin_amdgcn_readlane(s_l, i + q);
            f32x2 xv[8];
#pragma unroll
            for (int q = 0; q < 8; ++q)
                xv[q] = (f32x2){(float)xb[(size_t)s8[q] * CH + lane], 1.f};
#pragma unroll
            for (int hh = 0; hh < HEADS; ++hh) {
#pragma unroll
                for (int q = 0; q < 8; ++q) {
                    float wq = readlane_f(w[hh], i + q);
                    acc2[hh] += (f32x2){wq, wq} * xv[q];
                }
            }
        }
        for (; i + 3 < deg; i += 4) {
            int s0 = __builtin_amdgcn_readlane(s_l, i);
            int s1 = __builtin_amdgcn_readlane(s_l, i + 1);
            int s2 = __builtin_amdgcn_readlane(s_l, i + 2);
            int s3 = __builtin_amdgcn_readlane(s_l, i + 3);
            f32x2 xv0 = {(float)xb[(size_t)s0 * CH + lane], 1.f};
            f32x2 xv1 = {(float)xb[(size_t)s1 * CH + lane], 1.f};
            f32x2 xv2 = {(float)xb[(size_t)s2 * CH + lane], 1.f};
            f32x2 xv3 = {(float)xb[(size_t)s3 * CH + lane], 1.f};
#pragma unroll
            for (int hh = 0; hh < HEADS; ++hh) {
                float w0 = readlane_f(w[hh], i);
                float w1 = readlane_f(w[hh], i + 1);
                float w2 = readlane_f(w[hh], i + 2);
                float w3 = readlane_f(w[hh], i + 3);
                acc2[hh] += (f32x2){w0, w0} * xv0;
                acc2[hh] += (f32x2){w1, w1} * xv1;
                acc2[hh] += (f32x2){w2, w2} * xv2;
                acc2[hh] += (f32x2){w3, w3} * xv3;
            }
        }
        for (; i < deg; ++i) {
            int s = __builtin_amdgcn_readlane(s_l, i);
            f32x2 xv = {(float)xb[(size_t)s * CH + lane], 1.f};
#pragma unroll
            for (int hh = 0; hh < HEADS; ++hh) {
                float wv = readlane_f(w[hh], i);
                acc2[hh] += (f32x2){wv, wv} * xv;
            }
        }
        __bf16* zr = zt + row * ZSTRIDE + lane;
#pragma unroll
        for (int hh = 0; hh < HEADS; ++hh)
            zr[hh * CH] = (__bf16)(acc2[hh].x * (1.0f / ((acc2[hh].y + 1e-16f) * HEADS)));
    }

    __syncthreads();

    // ---- phase 3: 16x64x768 GEMM; wave = one 16-col tile ----
    {
        int m = lane & 15, quad = lane >> 4;
        int n0 = wave * 16;
        const __bf16* za = zt + m * ZSTRIDE + quad * 8;
        const __bf16* wb = Wt2 + (size_t)(n0 + m) * HC + quad * 8;
        f32x4 acc = {0.f, 0.f, 0.f, 0.f};
#pragma unroll
        for (int kc = 0; kc < HC; kc += 32) {
            bf16x8 a  = *(const bf16x8*)(za + kc);
            bf16x8 bf = *(const bf16x8*)(wb + kc);
            acc = __builtin_amdgcn_mfma_f32_16x16x32_bf16(a, bf, acc, 0, 0, 0);
        }
        int col = n0 + m;
        float bv = bias[col];
#pragma unroll
        for (int r = 0; r < 4; ++r) {
            int dd = base + quad * 4 + r;
            if (dd < N) {
                float o = x[(size_t)dd * CH + col] + acc[r] + bv;
                out[(size_t)dd * CH + col] = fmaxf(o, 0.f);
            }
        }
    }
}

extern "C" void kernel_launch(void* const* d_in, const int* in_sizes, int n_in,
                              void* d_out, int out_size, void* d_ws, size_t ws_size,
                              hipStream_t stream) {
    const float* x       = (const float*)d_in[0];
    const int*   ei      = (const int*)d_in[1];
    const float* W       = (const float*)d_in[2];
    const float* att_src = (const float*)d_in[3];
    const float* att_dst = (const float*)d_in[4];
    const float* bias    = (const float*)d_in[5];
    float* out = (float*)d_out;

    int N = in_sizes[0] / CH;   // 50000
    int E = in_sizes[1] / 2;    // 400000
    int EP = E + N;

    char* ws = (char*)d_ws;
    size_t off = 0;
    auto take = [&](size_t bytes) -> void* {
        void* p = ws + off;
        off = (off + bytes + 255) & ~(size_t)255;
        return p;
    };
    __bf16* xb    = (__bf16*)take((size_t)N * CH * sizeof(__bf16));
    __bf16* Wt2   = (__bf16*)take((size_t)CH * HC * sizeof(__bf16));
    __bf16* Vt    = (__bf16*)take((size_t)32 * CH * sizeof(__bf16));
    float*  a_all = (float*)take((size_t)N * ACOLS * sizeof(float));
    int*    adj   = (int*)take((size_t)N * CAP * sizeof(int));
    int*    cnt   = (int*)take((size_t)N * sizeof(int));

    const int nb_w     = (CH * HC) / 256;
    const int nb_build = (EP + EPT * 256 - 1) / (EPT * 256);   // 440
    const int nb_ax    = (N + 63) / 64;

    hipMemsetAsync(cnt, 0, (size_t)N * sizeof(int), stream);   // was k_pre blocks
    k_pre<<<nb_w + 32, 256, 0, stream>>>(W, att_src, att_dst, Wt2, Vt);
    k_build<<<nb_build, 256, 0, stream>>>(ei, cnt, adj, N, E);
    k_ax<<<nb_ax, 256, 0, stream>>>(x, Vt, xb, a_all, N);
    k_fused<<<(N + 15) / 16, 256, 0, stream>>>(cnt, adj, a_all, xb, Wt2, x, bias, out, N);
}

// Round 10
// 184.548 us; speedup vs baseline: 1.0358x; 1.0039x over previous
//
#include <hip/hip_runtime.h>
#include <hip/hip_bf16.h>

// GATConv N=50000, C=64, H=12, E=400000 (+N self loops), x-space aggregation:
//   y[d] = concat_h[ (sum_e w_eh x[s_e]) / (den_h*H) ] @ Wstack,  h never built.
// k_fused ~82us is a verified balance point: VALU-cut (R13/14/16), gather
//   depth (R17), TA-mask (R18), occupancy -- all neutral-or-worse. Its wall
//   time == VALU issue time (70% busy) with an equal latency floor beneath.
// R19 (this round): the LEDGER is the signal. total - k_fused ~= 95-102us
//   across 4 aux dispatches, each < 83us (never in top-5); traffic estimates
//   sum to ~40-60us -> tens of us lost to stream serialization of
//   INDEPENDENT kernels + launch gaps. Fix: k_mid = k_build U k_ax in one
//   block-partitioned dispatch (they share no data; build is atomic-latency-
//   bound, ax is MFMA-bound -> co-residency overlaps them). k_pre (tiny,
//   makes Vt for ax) stays ahead of it. k_fused reverted to exact R17 body
//   (best: 81.6-82.6us). Forcing move: if total stays ~185, k_mid must be
//   ~85-95us and WILL surface in top-5 with counters for next round.
// No segment_max: exp(s)/sum exp(s) is exact here (logits O(few), fp32 exp).

typedef __bf16 bf16x8 __attribute__((ext_vector_type(8)));
typedef float  f32x4  __attribute__((ext_vector_type(4)));
typedef float  f32x2  __attribute__((ext_vector_type(2)));

#define HEADS 12
#define CH 64
#define HC 768
#define CAP 64
#define ACOLS 24      // a_all[n][0..11]=src logits, [12..23]=dst logits
#define ZSTRIDE 776   // zt row stride (bf16)
#define EPT 4         // edges per thread in build part

__device__ inline float readlane_f(float v, int lane) {
    return __builtin_bit_cast(float,
        __builtin_amdgcn_readlane(__builtin_bit_cast(int, v), lane));
}

__global__ __launch_bounds__(256) void k_pre(
    const float* __restrict__ W,
    const float* __restrict__ att_src, const float* __restrict__ att_dst,
    __bf16* __restrict__ Wt2, __bf16* __restrict__ Vt) {
    const int nb_w = (CH * HC) >> 8;           // 192
    int b = blockIdx.x, tid = threadIdx.x;
    if (b < nb_w) {                            // ---- Wt2 transpose ----
        int t = b * 256 + tid;
        int c = t / HC, kk = t % HC;
        int k = kk & 63;
        Wt2[t] = (__bf16)W[(size_t)k * HC + (kk - k) + c];
        return;
    }
    b -= nb_w;                                 // ---- Vt col b (0..31) ----
    if (b >= 2 * HEADS) {
        if (tid < CH) Vt[b * CH + tid] = (__bf16)0.f;
        return;
    }
    const float* att = (b < HEADS) ? att_src + b * CH
                                   : att_dst + (b - HEADS) * CH;
    int k = tid >> 2, cq = tid & 3;            // 64 k-rows x 4 c-quarters
    const float* wr = W + (size_t)k * HC + (b % HEADS) * CH + cq * 16;
    float s = 0.f;
#pragma unroll
    for (int j = 0; j < 16; ++j) s += wr[j] * att[cq * 16 + j];
    s += __shfl_xor(s, 1, 64);
    s += __shfl_xor(s, 2, 64);
    if (cq == 0) Vt[b * CH + k] = (__bf16)s;
}

// ---- k_mid: block-partitioned {adjacency build | a_all=x@V + xb} ----
// The two halves are data-independent; fusing them into one dispatch gets
// hardware overlap of build's atomic latency with ax's MFMA/memory work,
// and removes one launch gap.
__global__ __launch_bounds__(256) void k_mid(
    const int* __restrict__ ei, const float* __restrict__ x,
    const __bf16* __restrict__ Vt,
    int* __restrict__ cnt, int* __restrict__ adj,
    __bf16* __restrict__ xb, float* __restrict__ a_all, int N, int E) {
    const int EP = E + N;
    const int nb_build = (EP + EPT * 256 - 1) / (EPT * 256);
    int b = blockIdx.x, tid = threadIdx.x;

    if (b < nb_build) {                        // ======== build part ========
        int tid0 = b * 256 + tid;
        int T = nb_build * 256;                // stride over BUILD blocks only
        int dv[EPT], sv[EPT];
#pragma unroll
        for (int k = 0; k < EPT; ++k) {        // phase A: loads in flight
            int e = tid0 + k * T;
            dv[k] = -1; sv[k] = 0;
            if (e < EP) {
                if (e < E) { dv[k] = ei[E + e]; sv[k] = ei[e]; }
                else       { dv[k] = e - E;     sv[k] = dv[k]; }
            }
        }
#pragma unroll
        for (int k = 0; k < EPT; ++k) {        // phase B: atomic+store chains
            if (dv[k] >= 0) {
                int pos = atomicAdd(&cnt[dv[k]], 1);
                if (pos < CAP) adj[dv[k] * CAP + pos] = sv[k];
            }
        }
        return;
    }
    b -= nb_build;                             // ======== ax part ========
    int wave = tid >> 6, lane = tid & 63;
    int m = lane & 15, quad = lane >> 4;
    int m0 = b * 64 + wave * 16;
    int row = m0 + m;
    int rc = row < N ? row : N - 1;
    const float* xa = x + (size_t)rc * CH + quad * 8;
    f32x4 v0 = *(const f32x4*)xa;
    f32x4 v1 = *(const f32x4*)(xa + 4);
    f32x4 v2 = *(const f32x4*)(xa + 32);
    f32x4 v3 = *(const f32x4*)(xa + 36);
    bf16x8 a0, a1;
#pragma unroll
    for (int j = 0; j < 4; ++j) {
        a0[j] = (__bf16)v0[j]; a0[4 + j] = (__bf16)v1[j];
        a1[j] = (__bf16)v2[j]; a1[4 + j] = (__bf16)v3[j];
    }
    if (row < N) {                             // fused xb = bf16(x)
        *(bf16x8*)(xb + (size_t)row * CH + quad * 8) = a0;
        *(bf16x8*)(xb + (size_t)row * CH + quad * 8 + 32) = a1;
    }
#pragma unroll
    for (int t = 0; t < 2; ++t) {              // two 16-col tiles -> 24 cols
        const __bf16* bp = Vt + (size_t)(t * 16 + m) * CH + quad * 8;
        bf16x8 b0 = *(const bf16x8*)bp;
        bf16x8 b1 = *(const bf16x8*)(bp + 32);
        f32x4 acc = {0.f, 0.f, 0.f, 0.f};
        acc = __builtin_amdgcn_mfma_f32_16x16x32_bf16(a0, b0, acc, 0, 0, 0);
        acc = __builtin_amdgcn_mfma_f32_16x16x32_bf16(a1, b1, acc, 0, 0, 0);
        int col = t * 16 + m;
        if (col < ACOLS) {
#pragma unroll
            for (int r = 0; r < 4; ++r) {
                int rr = m0 + quad * 4 + r;
                if (rr < N) a_all[(size_t)rr * ACOLS + col] = acc[r];
            }
        }
    }
}

__global__ __launch_bounds__(256) void k_fused(
    const int* __restrict__ cnt, const int* __restrict__ adj,
    const float* __restrict__ a_all,
    const __bf16* __restrict__ xb, const __bf16* __restrict__ Wt2,
    const float* __restrict__ x, const float* __restrict__ bias,
    float* __restrict__ out, int N) {
    __shared__ __bf16 zt[16 * ZSTRIDE];
    int lane = threadIdx.x & 63;
    int wave = __builtin_amdgcn_readfirstlane(threadIdx.x >> 6);
    int base = blockIdx.x * 16;

    // ---- prologue: 4 nodes' cnt + adj[0..31] in parallel ----
    int degj[4], slj[4];
#pragma unroll
    for (int j = 0; j < 4; ++j) {
        int d = base + wave * 4 + j;
        int dg = __builtin_amdgcn_readfirstlane(cnt[d]);
        degj[j] = dg < CAP ? dg : CAP;
        int sraw = 0;
        if (lane < 32) sraw = adj[d * CAP + lane];   // half row; poison past deg
        slj[j] = sraw;
    }

#pragma unroll
    for (int j = 0; j < 4; ++j) {
        int row = wave * 4 + j;
        int d = base + row;
        int deg = degj[j];
        int s_l = slj[j];
        if (deg > 32 && lane >= 32)              // ~never (Poisson(9))
            s_l = adj[d * CAP + lane];
        s_l = s_l < 0 ? 0 : (s_l >= N ? N - 1 : s_l);  // clamp poison

        // ---- phase 1: lane = edge slot; 12 weights in VGPRs ----
        float adf[HEADS];
        {
            const f32x4* p = (const f32x4*)(a_all + (size_t)d * ACOLS + HEADS);
            f32x4 t0 = p[0], t1 = p[1], t2 = p[2];
#pragma unroll
            for (int u = 0; u < 4; ++u) { adf[u] = t0[u]; adf[4 + u] = t1[u]; adf[8 + u] = t2[u]; }
        }
        float w[HEADS];
        {
            const f32x4* p = (const f32x4*)(a_all + (size_t)s_l * ACOLS);
            f32x4 t0 = p[0], t1 = p[1], t2 = p[2];
            float asf[HEADS];
#pragma unroll
            for (int u = 0; u < 4; ++u) { asf[u] = t0[u]; asf[4 + u] = t1[u]; asf[8 + u] = t2[u]; }
#pragma unroll
            for (int hh = 0; hh < HEADS; ++hh) {
                float sc = asf[hh] + adf[hh];
                sc = sc > 0.f ? sc : 0.2f * sc;
                w[hh] = __expf(sc);              // lanes >= deg never read
            }
        }

        // ---- phase 2: readlane broadcast, {acc,den} f32x2 packed ----
        f32x2 acc2[HEADS];
#pragma unroll
        for (int hh = 0; hh < HEADS; ++hh) acc2[hh] = (f32x2){0.f, 0.f};
        int i = 0;
        for (; i + 7 < deg; i += 8) {
            int s8[8];
#pragma unroll
            for (int q = 0; q < 8; ++q)
                s8[q] = __builtin_amdgcn_readlane(s_l, i + q);
            f32x2 xv[8];
#pragma unroll
            for (int q = 0; q < 8; ++q)
                xv[q] = (f32x2){(float)xb[(size_t)s8[q] * CH + lane], 1.f};
#pragma unroll
            for (int hh = 0; hh < HEADS; ++hh) {
#pragma unroll
                for (int q = 0; q < 8; ++q) {
                    float wq = readlane_f(w[hh], i + q);
                    acc2[hh] += (f32x2){wq, wq} * xv[q];
                }
            }
        }
        for (; i + 3 < deg; i += 4) {
            int s0 = __builtin_amdgcn_readlane(s_l, i);
            int s1 = __builtin_amdgcn_readlane(s_l, i + 1);
            int s2 = __builtin_amdgcn_readlane(s_l, i + 2);
            int s3 = __builtin_amdgcn_readlane(s_l, i + 3);
            f32x2 xv0 = {(float)xb[(size_t)s0 * CH + lane], 1.f};
            f32x2 xv1 = {(float)xb[(size_t)s1 * CH + lane], 1.f};
            f32x2 xv2 = {(float)xb[(size_t)s2 * CH + lane], 1.f};
            f32x2 xv3 = {(float)xb[(size_t)s3 * CH + lane], 1.f};
#pragma unroll
            for (int hh = 0; hh < HEADS; ++hh) {
                float w0 = readlane_f(w[hh], i);
                float w1 = readlane_f(w[hh], i + 1);
                float w2 = readlane_f(w[hh], i + 2);
                float w3 = readlane_f(w[hh], i + 3);
                acc2[hh] += (f32x2){w0, w0} * xv0;
                acc2[hh] += (f32x2){w1, w1} * xv1;
                acc2[hh] += (f32x2){w2, w2} * xv2;
                acc2[hh] += (f32x2){w3, w3} * xv3;
            }
        }
        for (; i < deg; ++i) {
            int s = __builtin_amdgcn_readlane(s_l, i);
            f32x2 xv = {(float)xb[(size_t)s * CH + lane], 1.f};
#pragma unroll
            for (int hh = 0; hh < HEADS; ++hh) {
                float wv = readlane_f(w[hh], i);
                acc2[hh] += (f32x2){wv, wv} * xv;
            }
        }
        __bf16* zr = zt + row * ZSTRIDE + lane;
#pragma unroll
        for (int hh = 0; hh < HEADS; ++hh)
            zr[hh * CH] = (__bf16)(acc2[hh].x * (1.0f / ((acc2[hh].y + 1e-16f) * HEADS)));
    }

    __syncthreads();

    // ---- phase 3: 16x64x768 GEMM; wave = one 16-col tile ----
    {
        int m = lane & 15, quad = lane >> 4;
        int n0 = wave * 16;
        const __bf16* za = zt + m * ZSTRIDE + quad * 8;
        const __bf16* wb = Wt2 + (size_t)(n0 + m) * HC + quad * 8;
        f32x4 acc = {0.f, 0.f, 0.f, 0.f};
#pragma unroll
        for (int kc = 0; kc < HC; kc += 32) {
            bf16x8 a  = *(const bf16x8*)(za + kc);
            bf16x8 bf = *(const bf16x8*)(wb + kc);
            acc = __builtin_amdgcn_mfma_f32_16x16x32_bf16(a, bf, acc, 0, 0, 0);
        }
        int col = n0 + m;
        float bv = bias[col];
#pragma unroll
        for (int r = 0; r < 4; ++r) {
            int dd = base + quad * 4 + r;
            if (dd < N) {
                float o = x[(size_t)dd * CH + col] + acc[r] + bv;
                out[(size_t)dd * CH + col] = fmaxf(o, 0.f);
            }
        }
    }
}

extern "C" void kernel_launch(void* const* d_in, const int* in_sizes, int n_in,
                              void* d_out, int out_size, void* d_ws, size_t ws_size,
                              hipStream_t stream) {
    const float* x       = (const float*)d_in[0];
    const int*   ei      = (const int*)d_in[1];
    const float* W       = (const float*)d_in[2];
    const float* att_src = (const float*)d_in[3];
    const float* att_dst = (const float*)d_in[4];
    const float* bias    = (const float*)d_in[5];
    float* out = (float*)d_out;

    int N = in_sizes[0] / CH;   // 50000
    int E = in_sizes[1] / 2;    // 400000
    int EP = E + N;

    char* ws = (char*)d_ws;
    size_t off = 0;
    auto take = [&](size_t bytes) -> void* {
        void* p = ws + off;
        off = (off + bytes + 255) & ~(size_t)255;
        return p;
    };
    __bf16* xb    = (__bf16*)take((size_t)N * CH * sizeof(__bf16));
    __bf16* Wt2   = (__bf16*)take((size_t)CH * HC * sizeof(__bf16));
    __bf16* Vt    = (__bf16*)take((size_t)32 * CH * sizeof(__bf16));
    float*  a_all = (float*)take((size_t)N * ACOLS * sizeof(float));
    int*    adj   = (int*)take((size_t)N * CAP * sizeof(int));
    int*    cnt   = (int*)take((size_t)N * sizeof(int));

    const int nb_w     = (CH * HC) / 256;                      // 192
    const int nb_build = (EP + EPT * 256 - 1) / (EPT * 256);   // 440
    const int nb_ax    = (N + 63) / 64;                        // 782

    hipMemsetAsync(cnt, 0, (size_t)N * sizeof(int), stream);
    k_pre<<<nb_w + 32, 256, 0, stream>>>(W, att_src, att_dst, Wt2, Vt);
    k_mid<<<nb_build + nb_ax, 256, 0, stream>>>(ei, x, Vt, cnt, adj, xb, a_all, N, E);
    k_fused<<<(N + 15) / 16, 256, 0, stream>>>(cnt, adj, a_all, xb, Wt2, x, bias, out, N);
}

// Round 11
// 174.538 us; speedup vs baseline: 1.0952x; 1.0574x over previous
//
#include <hip/hip_runtime.h>
#include <hip/hip_bf16.h>

// GATConv N=50000, C=64, H=12, E=400000 (+N self loops), x-space aggregation:
//   y[d] = concat_h[ (sum_e w_eh x[s_e]) / (den_h*H) ] @ Wstack,  h never built.
// SESSION LEDGER (R9..R19): k_fused is a verified balance point at ~82us --
//   VALU issue time == latency floor. Falsified by clean single-variable
//   tests: VALU-cut x3 (R13/14/16: VALUBusy 72->22% with NO time gain),
//   gather depth (R17), TA/poison mask (R18), occupancy, scratch,
//   uniformity. MFMA-aggregation restructures (R13/R14) pay a larger
//   latency penalty at deg~9/12-head granularity. Aux side ~92-102us
//   carries +-8us chip/run noise (R15 vs R17: identical aux kernels, 8.6us
//   apart); best total (175.4, R12) came from the 3-dispatch config.
// R20: consolidation. Minimum-dispatch structure (k_pre reabsorbs cnt=0,
//   drop memset; k_mid = build U ax block-partitioned) + best-measured
//   k_fused body (R17/R19). No new mechanisms.
// No segment_max: exp(s)/sum exp(s) is exact here (logits O(few), fp32 exp).

typedef __bf16 bf16x8 __attribute__((ext_vector_type(8)));
typedef float  f32x4  __attribute__((ext_vector_type(4)));
typedef float  f32x2  __attribute__((ext_vector_type(2)));

#define HEADS 12
#define CH 64
#define HC 768
#define CAP 64
#define ACOLS 24      // a_all[n][0..11]=src logits, [12..23]=dst logits
#define ZSTRIDE 776   // zt row stride (bf16)
#define EPT 4         // edges per thread in build part

__device__ inline float readlane_f(float v, int lane) {
    return __builtin_bit_cast(float,
        __builtin_amdgcn_readlane(__builtin_bit_cast(int, v), lane));
}

__global__ __launch_bounds__(256) void k_pre(
    const float* __restrict__ W,
    const float* __restrict__ att_src, const float* __restrict__ att_dst,
    int* __restrict__ cnt, __bf16* __restrict__ Wt2, __bf16* __restrict__ Vt,
    int N) {
    const int nb_z = (N + 255) >> 8;           // cnt = 0 (merged; no memset)
    const int nb_w = (CH * HC) >> 8;           // 192
    int b = blockIdx.x, tid = threadIdx.x;
    if (b < nb_z) {
        int i = b * 256 + tid;
        if (i < N) cnt[i] = 0;
        return;
    }
    b -= nb_z;
    if (b < nb_w) {                            // ---- Wt2 transpose ----
        int t = b * 256 + tid;
        int c = t / HC, kk = t % HC;
        int k = kk & 63;
        Wt2[t] = (__bf16)W[(size_t)k * HC + (kk - k) + c];
        return;
    }
    b -= nb_w;                                 // ---- Vt col b (0..31) ----
    if (b >= 2 * HEADS) {
        if (tid < CH) Vt[b * CH + tid] = (__bf16)0.f;
        return;
    }
    const float* att = (b < HEADS) ? att_src + b * CH
                                   : att_dst + (b - HEADS) * CH;
    int k = tid >> 2, cq = tid & 3;            // 64 k-rows x 4 c-quarters
    const float* wr = W + (size_t)k * HC + (b % HEADS) * CH + cq * 16;
    float s = 0.f;
#pragma unroll
    for (int j = 0; j < 16; ++j) s += wr[j] * att[cq * 16 + j];
    s += __shfl_xor(s, 1, 64);
    s += __shfl_xor(s, 2, 64);
    if (cq == 0) Vt[b * CH + k] = (__bf16)s;
}

// ---- k_mid: block-partitioned {adjacency build | a_all=x@V + xb} ----
__global__ __launch_bounds__(256) void k_mid(
    const int* __restrict__ ei, const float* __restrict__ x,
    const __bf16* __restrict__ Vt,
    int* __restrict__ cnt, int* __restrict__ adj,
    __bf16* __restrict__ xb, float* __restrict__ a_all, int N, int E) {
    const int EP = E + N;
    const int nb_build = (EP + EPT * 256 - 1) / (EPT * 256);
    int b = blockIdx.x, tid = threadIdx.x;

    if (b < nb_build) {                        // ======== build part ========
        int tid0 = b * 256 + tid;
        int T = nb_build * 256;                // stride over BUILD blocks only
        int dv[EPT], sv[EPT];
#pragma unroll
        for (int k = 0; k < EPT; ++k) {        // phase A: loads in flight
            int e = tid0 + k * T;
            dv[k] = -1; sv[k] = 0;
            if (e < EP) {
                if (e < E) { dv[k] = ei[E + e]; sv[k] = ei[e]; }
                else       { dv[k] = e - E;     sv[k] = dv[k]; }
            }
        }
#pragma unroll
        for (int k = 0; k < EPT; ++k) {        // phase B: atomic+store chains
            if (dv[k] >= 0) {
                int pos = atomicAdd(&cnt[dv[k]], 1);
                if (pos < CAP) adj[dv[k] * CAP + pos] = sv[k];
            }
        }
        return;
    }
    b -= nb_build;                             // ======== ax part ========
    int wave = tid >> 6, lane = tid & 63;
    int m = lane & 15, quad = lane >> 4;
    int m0 = b * 64 + wave * 16;
    int row = m0 + m;
    int rc = row < N ? row : N - 1;
    const float* xa = x + (size_t)rc * CH + quad * 8;
    f32x4 v0 = *(const f32x4*)xa;
    f32x4 v1 = *(const f32x4*)(xa + 4);
    f32x4 v2 = *(const f32x4*)(xa + 32);
    f32x4 v3 = *(const f32x4*)(xa + 36);
    bf16x8 a0, a1;
#pragma unroll
    for (int j = 0; j < 4; ++j) {
        a0[j] = (__bf16)v0[j]; a0[4 + j] = (__bf16)v1[j];
        a1[j] = (__bf16)v2[j]; a1[4 + j] = (__bf16)v3[j];
    }
    if (row < N) {                             // fused xb = bf16(x)
        *(bf16x8*)(xb + (size_t)row * CH + quad * 8) = a0;
        *(bf16x8*)(xb + (size_t)row * CH + quad * 8 + 32) = a1;
    }
#pragma unroll
    for (int t = 0; t < 2; ++t) {              // two 16-col tiles -> 24 cols
        const __bf16* bp = Vt + (size_t)(t * 16 + m) * CH + quad * 8;
        bf16x8 b0 = *(const bf16x8*)bp;
        bf16x8 b1 = *(const bf16x8*)(bp + 32);
        f32x4 acc = {0.f, 0.f, 0.f, 0.f};
        acc = __builtin_amdgcn_mfma_f32_16x16x32_bf16(a0, b0, acc, 0, 0, 0);
        acc = __builtin_amdgcn_mfma_f32_16x16x32_bf16(a1, b1, acc, 0, 0, 0);
        int col = t * 16 + m;
        if (col < ACOLS) {
#pragma unroll
            for (int r = 0; r < 4; ++r) {
                int rr = m0 + quad * 4 + r;
                if (rr < N) a_all[(size_t)rr * ACOLS + col] = acc[r];
            }
        }
    }
}

__global__ __launch_bounds__(256) void k_fused(
    const int* __restrict__ cnt, const int* __restrict__ adj,
    const float* __restrict__ a_all,
    const __bf16* __restrict__ xb, const __bf16* __restrict__ Wt2,
    const float* __restrict__ x, const float* __restrict__ bias,
    float* __restrict__ out, int N) {
    __shared__ __bf16 zt[16 * ZSTRIDE];
    int lane = threadIdx.x & 63;
    int wave = __builtin_amdgcn_readfirstlane(threadIdx.x >> 6);
    int base = blockIdx.x * 16;

    // ---- prologue: 4 nodes' cnt + adj[0..31] in parallel ----
    int degj[4], slj[4];
#pragma unroll
    for (int j = 0; j < 4; ++j) {
        int d = base + wave * 4 + j;
        int dg = __builtin_amdgcn_readfirstlane(cnt[d]);
        degj[j] = dg < CAP ? dg : CAP;
        int sraw = 0;
        if (lane < 32) sraw = adj[d * CAP + lane];   // half row; poison past deg
        slj[j] = sraw;
    }

#pragma unroll
    for (int j = 0; j < 4; ++j) {
        int row = wave * 4 + j;
        int d = base + row;
        int deg = degj[j];
        int s_l = slj[j];
        if (deg > 32 && lane >= 32)              // ~never (Poisson(9))
            s_l = adj[d * CAP + lane];
        s_l = s_l < 0 ? 0 : (s_l >= N ? N - 1 : s_l);  // clamp poison

        // ---- phase 1: lane = edge slot; 12 weights in VGPRs ----
        float adf[HEADS];
        {
            const f32x4* p = (const f32x4*)(a_all + (size_t)d * ACOLS + HEADS);
            f32x4 t0 = p[0], t1 = p[1], t2 = p[2];
#pragma unroll
            for (int u = 0; u < 4; ++u) { adf[u] = t0[u]; adf[4 + u] = t1[u]; adf[8 + u] = t2[u]; }
        }
        float w[HEADS];
        {
            const f32x4* p = (const f32x4*)(a_all + (size_t)s_l * ACOLS);
            f32x4 t0 = p[0], t1 = p[1], t2 = p[2];
            float asf[HEADS];
#pragma unroll
            for (int u = 0; u < 4; ++u) { asf[u] = t0[u]; asf[4 + u] = t1[u]; asf[8 + u] = t2[u]; }
#pragma unroll
            for (int hh = 0; hh < HEADS; ++hh) {
                float sc = asf[hh] + adf[hh];
                sc = sc > 0.f ? sc : 0.2f * sc;
                w[hh] = __expf(sc);              // lanes >= deg never read
            }
        }

        // ---- phase 2: readlane broadcast, {acc,den} f32x2 packed ----
        f32x2 acc2[HEADS];
#pragma unroll
        for (int hh = 0; hh < HEADS; ++hh) acc2[hh] = (f32x2){0.f, 0.f};
        int i = 0;
        for (; i + 7 < deg; i += 8) {
            int s8[8];
#pragma unroll
            for (int q = 0; q < 8; ++q)
                s8[q] = __builtin_amdgcn_readlane(s_l, i + q);
            f32x2 xv[8];
#pragma unroll
            for (int q = 0; q < 8; ++q)
                xv[q] = (f32x2){(float)xb[(size_t)s8[q] * CH + lane], 1.f};
#pragma unroll
            for (int hh = 0; hh < HEADS; ++hh) {
#pragma unroll
                for (int q = 0; q < 8; ++q) {
                    float wq = readlane_f(w[hh], i + q);
                    acc2[hh] += (f32x2){wq, wq} * xv[q];
                }
            }
        }
        for (; i + 3 < deg; i += 4) {
            int s0 = __builtin_amdgcn_readlane(s_l, i);
            int s1 = __builtin_amdgcn_readlane(s_l, i + 1);
            int s2 = __builtin_amdgcn_readlane(s_l, i + 2);
            int s3 = __builtin_amdgcn_readlane(s_l, i + 3);
            f32x2 xv0 = {(float)xb[(size_t)s0 * CH + lane], 1.f};
            f32x2 xv1 = {(float)xb[(size_t)s1 * CH + lane], 1.f};
            f32x2 xv2 = {(float)xb[(size_t)s2 * CH + lane], 1.f};
            f32x2 xv3 = {(float)xb[(size_t)s3 * CH + lane], 1.f};
#pragma unroll
            for (int hh = 0; hh < HEADS; ++hh) {
                float w0 = readlane_f(w[hh], i);
                float w1 = readlane_f(w[hh], i + 1);
                float w2 = readlane_f(w[hh], i + 2);
                float w3 = readlane_f(w[hh], i + 3);
                acc2[hh] += (f32x2){w0, w0} * xv0;
                acc2[hh] += (f32x2){w1, w1} * xv1;
                acc2[hh] += (f32x2){w2, w2} * xv2;
                acc2[hh] += (f32x2){w3, w3} * xv3;
            }
        }
        for (; i < deg; ++i) {
            int s = __builtin_amdgcn_readlane(s_l, i);
            f32x2 xv = {(float)xb[(size_t)s * CH + lane], 1.f};
#pragma unroll
            for (int hh = 0; hh < HEADS; ++hh) {
                float wv = readlane_f(w[hh], i);
                acc2[hh] += (f32x2){wv, wv} * xv;
            }
        }
        __bf16* zr = zt + row * ZSTRIDE + lane;
#pragma unroll
        for (int hh = 0; hh < HEADS; ++hh)
            zr[hh * CH] = (__bf16)(acc2[hh].x * (1.0f / ((acc2[hh].y + 1e-16f) * HEADS)));
    }

    __syncthreads();

    // ---- phase 3: 16x64x768 GEMM; wave = one 16-col tile ----
    {
        int m = lane & 15, quad = lane >> 4;
        int n0 = wave * 16;
        const __bf16* za = zt + m * ZSTRIDE + quad * 8;
        const __bf16* wb = Wt2 + (size_t)(n0 + m) * HC + quad * 8;
        f32x4 acc = {0.f, 0.f, 0.f, 0.f};
#pragma unroll
        for (int kc = 0; kc < HC; kc += 32) {
            bf16x8 a  = *(const bf16x8*)(za + kc);
            bf16x8 bf = *(const bf16x8*)(wb + kc);
            acc = __builtin_amdgcn_mfma_f32_16x16x32_bf16(a, bf, acc, 0, 0, 0);
        }
        int col = n0 + m;
        float bv = bias[col];
#pragma unroll
        for (int r = 0; r < 4; ++r) {
            int dd = base + quad * 4 + r;
            if (dd < N) {
                float o = x[(size_t)dd * CH + col] + acc[r] + bv;
                out[(size_t)dd * CH + col] = fmaxf(o, 0.f);
            }
        }
    }
}

extern "C" void kernel_launch(void* const* d_in, const int* in_sizes, int n_in,
                              void* d_out, int out_size, void* d_ws, size_t ws_size,
                              hipStream_t stream) {
    const float* x       = (const float*)d_in[0];
    const int*   ei      = (const int*)d_in[1];
    const float* W       = (const float*)d_in[2];
    const float* att_src = (const float*)d_in[3];
    const float* att_dst = (const float*)d_in[4];
    const float* bias    = (const float*)d_in[5];
    float* out = (float*)d_out;

    int N = in_sizes[0] / CH;   // 50000
    int E = in_sizes[1] / 2;    // 400000
    int EP = E + N;

    char* ws = (char*)d_ws;
    size_t off = 0;
    auto take = [&](size_t bytes) -> void* {
        void* p = ws + off;
        off = (off + bytes + 255) & ~(size_t)255;
        return p;
    };
    __bf16* xb    = (__bf16*)take((size_t)N * CH * sizeof(__bf16));
    __bf16* Wt2   = (__bf16*)take((size_t)CH * HC * sizeof(__bf16));
    __bf16* Vt    = (__bf16*)take((size_t)32 * CH * sizeof(__bf16));
    float*  a_all = (float*)take((size_t)N * ACOLS * sizeof(float));
    int*    adj   = (int*)take((size_t)N * CAP * sizeof(int));
    int*    cnt   = (int*)take((size_t)N * sizeof(int));

    const int nb_z     = (N + 255) / 256;                      // 196
    const int nb_w     = (CH * HC) / 256;                      // 192
    const int nb_build = (EP + EPT * 256 - 1) / (EPT * 256);   // 440
    const int nb_ax    = (N + 63) / 64;                        // 782

    k_pre<<<nb_z + nb_w + 32, 256, 0, stream>>>(W, att_src, att_dst, cnt, Wt2, Vt, N);
    k_mid<<<nb_build + nb_ax, 256, 0, stream>>>(ei, x, Vt, cnt, adj, xb, a_all, N, E);
    k_fused<<<(N + 15) / 16, 256, 0, stream>>>(cnt, adj, a_all, xb, Wt2, x, bias, out, N);
}